// Round 2
// baseline (444.274 us; speedup 1.0000x reference)
//
#include <hip/hip_runtime.h>

// ---------------------------------------------------------------------------
// Generator head, fused:
//   FC(1024->7056) + Conv2x2'same' folded into one bf16 GEMM
//   (M=8192, N=3136 pad 3200, K=1024), epilogue = +bias, LeakyReLU,
//   bf16 store TRANSPOSED (h2T[n][m], batch-contiguous) + fused per-column
//   BN statistics (atomics). Then a 1-block BN scale/shift reduce, then two
//   batch-per-lane locally-connected convs with wave-uniform (s_load) weights.
// ---------------------------------------------------------------------------

#define SLOPE 0.01f

typedef __bf16 bf16x8 __attribute__((ext_vector_type(8)));
typedef float f32x4 __attribute__((ext_vector_type(4)));

typedef const __attribute__((address_space(1))) void* gas_ptr;
typedef __attribute__((address_space(3))) void* las_ptr;

__device__ __forceinline__ void load16_to_lds(const void* g, void* l) {
  __builtin_amdgcn_global_load_lds((gas_ptr)g, (las_ptr)l, 16, 0, 0);
}

__device__ __forceinline__ unsigned short f2bf(float f) {
  union { float f; unsigned int u; } v; v.f = f;
  unsigned int r = v.u + 0x7FFFu + ((v.u >> 16) & 1u);
  return (unsigned short)(r >> 16);
}
__device__ __forceinline__ float bfbits2f(unsigned int bits16) {
  union { unsigned int u; float f; } v; v.u = bits16 << 16;
  return v.f;
}
__device__ __forceinline__ float leaky(float v) { return v >= 0.f ? v : SLOPE * v; }

// --------------------------- K0: cast x to bf16 ----------------------------
__global__ void k_cast_x(const float* __restrict__ x, unsigned short* __restrict__ xb,
                         float* __restrict__ stats_col) {
  if (blockIdx.x == 0)  // zero per-column BN accumulators (6400 floats)
    for (int i = threadIdx.x; i < 6400; i += 256) stats_col[i] = 0.f;
  int gid = blockIdx.x * 256 + threadIdx.x;             // 8.4M floats / 8 per thread
  const float4* x4 = (const float4*)x;
  float4 a = x4[gid * 2], b = x4[gid * 2 + 1];
  union { unsigned short s[8]; uint4 v; } o;
  o.s[0] = f2bf(a.x); o.s[1] = f2bf(a.y); o.s[2] = f2bf(a.z); o.s[3] = f2bf(a.w);
  o.s[4] = f2bf(b.x); o.s[5] = f2bf(b.y); o.s[6] = f2bf(b.z); o.s[7] = f2bf(b.w);
  ((uint4*)xb)[gid] = o.v;
}

// ------------------- K1: fold conv into fc -> Wc (bf16), bc ----------------
// Wc row n = o*196 + i*14 + j (o<16, i<14, j<14), K=1024; rows [3136,3200) zero.
// Grid (4 k-quarters, 197 spatial); thread owns one k column.
__global__ void k_fold(const float* __restrict__ fc_w, const float* __restrict__ fc_b,
                       const float* __restrict__ conv_w, const float* __restrict__ conv_b,
                       unsigned short* __restrict__ Wc, float* __restrict__ bc) {
  int blk = blockIdx.y, kq = blockIdx.x, t = threadIdx.x;
  if (blk == 196) {  // zero pad rows
    uint4 z = make_uint4(0, 0, 0, 0);
    for (int i = t; i < 64 * 64; i += 256) {           // 64 rows x 64 uint4
      int r = i >> 6, qq = i & 63;
      *(uint4*)(Wc + (3136 + r) * 1024 + kq * 256 + qq * 8) = z;
    }
    if (kq == 0) for (int i = 3136 + t; i < 3200; i += 256) bc[i] = 0.f;
    return;
  }
  __shared__ float cw[2304];  // 16*36*2*2
  for (int i = t; i < 2304; i += 256) cw[i] = conv_w[i];
  __syncthreads();
  int i0 = blk / 14, j0 = blk - (blk / 14) * 14;
  int k = kq * 256 + t;
  float acc[16];
#pragma unroll
  for (int o = 0; o < 16; o++) acc[o] = 0.f;
  for (int c = 0; c < 36; c++) {
#pragma unroll
    for (int dy = 0; dy < 2; dy++) {
      int ii = i0 + dy; if (ii > 13) continue;
#pragma unroll
      for (int dx = 0; dx < 2; dx++) {
        int jj = j0 + dx; if (jj > 13) continue;
        float f = fc_w[((ii * 14 + jj) * 36 + c) * 1024 + k];
        int kk = dy * 2 + dx;
#pragma unroll
        for (int o = 0; o < 16; o++) acc[o] += cw[(o * 36 + c) * 4 + kk] * f;
      }
    }
  }
#pragma unroll
  for (int o = 0; o < 16; o++)
    Wc[(o * 196 + i0 * 14 + j0) * 1024 + k] = f2bf(acc[o]);
  if (kq == 0 && t < 16) {
    int o = t;
    float b = conv_b[o];
    for (int c = 0; c < 36; c++)
      for (int dy = 0; dy < 2; dy++) {
        int ii = i0 + dy; if (ii > 13) continue;
        for (int dx = 0; dx < 2; dx++) {
          int jj = j0 + dx; if (jj > 13) continue;
          b += cw[(o * 36 + c) * 4 + dy * 2 + dx] * fc_b[(ii * 14 + jj) * 36 + c];
        }
      }
    bc[o * 196 + i0 * 14 + j0] = b;
  }
}

// --------------------------- K2: bf16 MFMA GEMM ----------------------------
// C[m][n] = sum_k Xb[m][k] * Wc[n][k];  epilogue: +bc[n], leaky, store to
// h2T[n*8192+m] (bf16), and accumulate per-column sum/sumsq into stats_col.
// 1-D grid, y-major order: each XCD's round-robin share is a fixed 8-row
// A band (2 MB -> L2-resident) while B streams.
__global__ __launch_bounds__(256, 2) void k_gemm(const unsigned short* __restrict__ Xb,
                                                 const unsigned short* __restrict__ Wcb,
                                                 const float* __restrict__ bc,
                                                 unsigned short* __restrict__ h2,
                                                 float* __restrict__ stats_col) {
  __shared__ __align__(16) char lds[16384];  // A: [0,8K), B: [8K,16K)
  const int t = threadIdx.x;
  const int w = t >> 6, lane = t & 63;
  const int quad = lane >> 4, l15 = lane & 15;
  const int lid = blockIdx.x;
  const int m0 = (lid & 63) * 128, n0 = (lid >> 6) * 128;  // y-major
  const int mrow = t & 127, tko = t >> 7;  // staging: row in tile, base ko
  const unsigned short* ga = Xb + (m0 + mrow) * 1024 + tko * 8;
  const unsigned short* gb = Wcb + (n0 + mrow) * 1024 + tko * 8;
  char* lA = lds;
  char* lB = lds + 8192;
  const int wbase = w * 1024;
  const int wm0 = (w >> 1) * 64, wn0 = (w & 1) * 64;

  f32x4 acc[4][4];
#pragma unroll
  for (int a = 0; a < 4; a++)
#pragma unroll
    for (int b = 0; b < 4; b++) acc[a][b] = (f32x4){0.f, 0.f, 0.f, 0.f};

  for (int kb = 0; kb < 1024; kb += 32) {
    __syncthreads();
    load16_to_lds(ga + kb,      lA + wbase);
    load16_to_lds(ga + kb + 16, lA + 4096 + wbase);
    load16_to_lds(gb + kb,      lB + wbase);
    load16_to_lds(gb + kb + 16, lB + 4096 + wbase);
    __syncthreads();

    bf16x8 af[4], bfr[4];
#pragma unroll
    for (int mb = 0; mb < 4; mb++)
      af[mb] = *(const bf16x8*)(lA + quad * 2048 + (wm0 + mb * 16 + l15) * 16);
#pragma unroll
    for (int nb = 0; nb < 4; nb++)
      bfr[nb] = *(const bf16x8*)(lB + quad * 2048 + (wn0 + nb * 16 + l15) * 16);
#pragma unroll
    for (int mb = 0; mb < 4; mb++)
#pragma unroll
      for (int nb = 0; nb < 4; nb++)
        acc[mb][nb] = __builtin_amdgcn_mfma_f32_16x16x32_bf16(af[mb], bfr[nb], acc[mb][nb], 0, 0, 0);
  }

#pragma unroll
  for (int nb = 0; nb < 4; nb++) {
    int col = n0 + wn0 + nb * 16 + l15;
    float bias = bc[col];
    float s = 0.f, s2 = 0.f;
    unsigned short* base = h2 + col * 8192 + m0 + wm0 + quad * 4;
#pragma unroll
    for (int mb = 0; mb < 4; mb++) {
      union { unsigned short u[4]; uint2 v; } pk;
#pragma unroll
      for (int r = 0; r < 4; r++) {
        float v = leaky(acc[mb][nb][r] + bias);   // row = wm0+mb*16+quad*4+r
        s += v; s2 += v * v;
        pk.u[r] = f2bf(v);
      }
      *(uint2*)(base + mb * 16) = pk.v;           // 8B store, m-contiguous
    }
    // reduce the 4 quads (same col, disjoint rows) then one atomic per col
    s  += __shfl_xor(s, 16, 64);  s  += __shfl_xor(s, 32, 64);
    s2 += __shfl_xor(s2, 16, 64); s2 += __shfl_xor(s2, 32, 64);
    if (quad == 0) {
      atomicAdd(&stats_col[col], s);
      atomicAdd(&stats_col[3200 + col], s2);
    }
  }
}

// ----------------- K3: reduce per-column stats -> BN scale/shift -----------
__global__ void k_bnscale(const float* __restrict__ stats_col,
                          const float* __restrict__ gamma, const float* __restrict__ beta,
                          float* __restrict__ scbuf) {
  __shared__ float chs[16], chs2[16];
  int t = threadIdx.x;
  if (t < 16) { chs[t] = 0.f; chs2[t] = 0.f; }
  __syncthreads();
  for (int col = t; col < 3136; col += 256) {
    int o = col / 196;
    atomicAdd(&chs[o], stats_col[col]);
    atomicAdd(&chs2[o], stats_col[3200 + col]);
  }
  __syncthreads();
  if (t < 16) {
    const float inv = 1.f / 1605632.f;  // 8192*196
    float mean = chs[t] * inv;
    float var = chs2[t] * inv - mean * mean;
    float sc = gamma[t] * rsqrtf(var + 1e-5f);
    scbuf[t] = sc; scbuf[16 + t] = beta[t] - mean * sc;
  }
}

// ------------- K4: BN-apply + local conv1 + leaky  (batch-per-lane) --------
// Grid (128 m-windows, 13 y). Wave-uniform weights -> s_load broadcasts.
__global__ __launch_bounds__(64) void k_tail1(const unsigned short* __restrict__ h2,
                                              const float* __restrict__ scbuf,
                                              const float* __restrict__ lw1,
                                              unsigned short* __restrict__ h4) {
  const int m = blockIdx.x * 64 + threadIdx.x;
  const int y = blockIdx.y;                     // 0..12
  float acc[6][13];
#pragma unroll
  for (int o = 0; o < 6; o++)
#pragma unroll
    for (int x = 0; x < 13; x++) acc[o][x] = 0.f;

  for (int c = 0; c < 16; c++) {
    float scc = scbuf[c], shc = scbuf[16 + c];
    const unsigned short* p0 = h2 + (c * 196 + y * 14) * 8192 + m;
    float r0[14], r1[14];
#pragma unroll
    for (int x = 0; x < 14; x++) {
      r0[x] = bfbits2f(p0[x * 8192]) * scc + shc;
      r1[x] = bfbits2f(p0[(14 + x) * 8192]) * scc + shc;
    }
#pragma unroll
    for (int o = 0; o < 6; o++) {
      const float* wp = lw1 + (((o * 16 + c) * 13 + y) * 13) * 4;  // uniform -> s_load
#pragma unroll
      for (int x = 0; x < 13; x++)
        acc[o][x] += r0[x] * wp[4 * x] + r0[x + 1] * wp[4 * x + 1] +
                     r1[x] * wp[4 * x + 2] + r1[x + 1] * wp[4 * x + 3];
    }
  }
  unsigned short* q = h4 + y * 13 * 8192 + m;   // row (o*13+y)*13+x
#pragma unroll
  for (int o = 0; o < 6; o++)
#pragma unroll
    for (int x = 0; x < 13; x++)
      q[(o * 169 + x) * 8192] = f2bf(leaky(acc[o][x]));
}

// ------------------------- K5: local conv2 (batch-per-lane) ----------------
// Grid (128 m-windows, 3); wave w handles y2 = blockIdx.y*4 + w (0..11).
__global__ __launch_bounds__(256) void k_tail2(const unsigned short* __restrict__ h4,
                                               const float* __restrict__ lw2,
                                               float* __restrict__ out) {
  const int lane = threadIdx.x & 63, w = threadIdx.x >> 6;
  const int m = blockIdx.x * 64 + lane;
  const int y = blockIdx.y * 4 + w;             // 0..11
  float acc[12];
#pragma unroll
  for (int x = 0; x < 12; x++) acc[x] = 0.f;
  for (int c = 0; c < 6; c++) {
    const unsigned short* p = h4 + (c * 13 + y) * 13 * 8192 + m;
    float r0[13], r1[13];
#pragma unroll
    for (int x = 0; x < 13; x++) {
      r0[x] = bfbits2f(p[x * 8192]);
      r1[x] = bfbits2f(p[(13 + x) * 8192]);
    }
    const float* wp = lw2 + ((c * 12 + y) * 12) * 4;  // uniform -> s_load
#pragma unroll
    for (int x = 0; x < 12; x++)
      acc[x] += r0[x] * wp[4 * x] + r0[x + 1] * wp[4 * x + 1] +
                r1[x] * wp[4 * x + 2] + r1[x + 1] * wp[4 * x + 3];
  }
  float* op = out + m * 144 + y * 12;
#pragma unroll
  for (int x = 0; x < 12; x++) op[x] = acc[x];
}

// ---------------------------------------------------------------------------
extern "C" void kernel_launch(void* const* d_in, const int* in_sizes, int n_in,
                              void* d_out, int out_size, void* d_ws, size_t ws_size,
                              hipStream_t stream) {
  const float* x      = (const float*)d_in[0];
  const float* fc_w   = (const float*)d_in[1];
  const float* fc_b   = (const float*)d_in[2];
  const float* conv_w = (const float*)d_in[3];
  const float* conv_b = (const float*)d_in[4];
  const float* gamma  = (const float*)d_in[5];
  const float* beta   = (const float*)d_in[6];
  const float* lw1    = (const float*)d_in[7];
  const float* lw2    = (const float*)d_in[8];

  char* ws = (char*)d_ws;
  // workspace layout (75.8 MB total)
  unsigned short* Xb        = (unsigned short*)(ws);            // 16,777,216 B
  unsigned short* h4T       = (unsigned short*)(ws);            // overlays Xb (used after gemm)
  unsigned short* Wc        = (unsigned short*)(ws + 16777216); //  6,553,600 B
  float*          bc        = (float*)(ws + 23330816);          //     12,800 B
  float*          stats_col = (float*)(ws + 23343616);          //     25,600 B
  float*          scbuf     = (float*)(ws + 23369216);          //        128 B
  unsigned short* h2T       = (unsigned short*)(ws + 23369344); // 52,428,800 B

  k_cast_x<<<4096, 256, 0, stream>>>(x, Xb, stats_col);
  k_fold<<<dim3(4, 197), 256, 0, stream>>>(fc_w, fc_b, conv_w, conv_b, Wc, bc);
  k_gemm<<<1600, 256, 0, stream>>>(Xb, Wc, bc, h2T, stats_col);
  k_bnscale<<<1, 256, 0, stream>>>(stats_col, gamma, beta, scbuf);
  k_tail1<<<dim3(128, 13), 64, 0, stream>>>(h2T, scbuf, lw1, h4T);
  k_tail2<<<dim3(128, 3), 256, 0, stream>>>(h4T, lw2, (float*)d_out);
}